// Round 2
// baseline (434.280 us; speedup 1.0000x reference)
//
#include <hip/hip_runtime.h>
#include <hip/hip_bf16.h>
#include <cstdint>

// ---------------------------------------------------------------------------
// W8A8 linear: y = (int8_gemm(quant(x), W^T)) * alpha
//   x: fp32 [M=8192, K=4096]
//   W: int8 in reference, but harness materializes integer inputs as int32
//      -> d_in[1] is const int* [N=4096, K] ; we pack to int8 in d_ws first.
//   q = clip(rint(x / inscale), -128, 127) int8
// ---------------------------------------------------------------------------

typedef int v4i __attribute__((ext_vector_type(4)));

#define BM 128
#define BN 128
#define BK 64          // one MFMA K-step (16x16x64 i8)
#define NTHREADS 256

// ---- pack weight: int32 -> int8, 16 elements per thread -------------------
__global__ void pack_w_kernel(const int* __restrict__ w32,
                              signed char* __restrict__ w8,
                              int n_chunks) {
    int i = blockIdx.x * blockDim.x + threadIdx.x;
    if (i >= n_chunks) return;
    const int4* wv = (const int4*)w32 + (size_t)i * 4;
    union { signed char c[16]; int4 v; } u;
#pragma unroll
    for (int j = 0; j < 4; ++j) {
        int4 w = wv[j];
        u.c[j * 4 + 0] = (signed char)w.x;
        u.c[j * 4 + 1] = (signed char)w.y;
        u.c[j * 4 + 2] = (signed char)w.z;
        u.c[j * 4 + 3] = (signed char)w.w;
    }
    ((int4*)w8)[i] = u.v;
}

// ---- quantization: 16 elements per thread ---------------------------------
__global__ void quant_kernel(const float* __restrict__ x,
                             signed char* __restrict__ q,
                             const float* __restrict__ inscale_ptr,
                             int n_chunks) {
    int i = blockIdx.x * blockDim.x + threadIdx.x;
    if (i >= n_chunks) return;
    const float s = *inscale_ptr;                 // scalar, L2-cached
    const float4* xv = (const float4*)x + (size_t)i * 4;
    union { signed char c[16]; int4 v; } u;
#pragma unroll
    for (int j = 0; j < 4; ++j) {
        float4 f = xv[j];
        float vals[4] = {f.x, f.y, f.z, f.w};
#pragma unroll
        for (int e = 0; e < 4; ++e) {
            // IEEE divide + rint (round-half-even) matches np.round(xf/inscale)
            float r = rintf(vals[e] / s);
            r = fminf(fmaxf(r, -128.0f), 127.0f);
            u.c[j * 4 + e] = (signed char)(int)r;
        }
    }
    ((int4*)q)[i] = u.v;
}

// ---- async global->LDS, 16B per lane --------------------------------------
__device__ __forceinline__ void async16(void* lds, const void* g) {
    __builtin_amdgcn_global_load_lds(
        (const __attribute__((address_space(1))) void*)g,
        (__attribute__((address_space(3))) void*)lds,
        16, 0, 0);
}

// ---- int8 GEMM: C[m,n] = sum_k A[m,k]*W[n,k], epilogue *alpha -> fp32 -----
__global__ __launch_bounds__(NTHREADS)
void w8a8_gemm(const signed char* __restrict__ A,   // [M,K] quantized acts
               const signed char* __restrict__ Bw,  // [N,K] packed weights
               float* __restrict__ C,               // [M,N] fp32 out
               const float* __restrict__ alpha_ptr,
               int M, int N, int K) {
    __shared__ signed char lA[BM * BK];   // 8 KiB, contiguous (global_load_lds)
    __shared__ signed char lB[BN * BK];   // 8 KiB

    const int t    = threadIdx.x;
    const int lane = t & 63;
    const int wave = t >> 6;
    const int wm   = (wave >> 1) * 64;    // wave's row offset in tile (2x2 waves)
    const int wn   = (wave & 1) * 64;

    const int tileM = blockIdx.y * BM;
    const int tileN = blockIdx.x * BN;

    // staging: tile is 128 rows x 64 bytes = 8192 B; 256 thr x 16 B = 4096 B/step
    const int sIdx0 = t * 16;             // step-0 byte index in tile
    const int sIdx1 = sIdx0 + 4096;       // step-1
    const int r0 = sIdx0 >> 6, c0 = sIdx0 & 63;
    const int r1 = sIdx1 >> 6, c1 = sIdx1 & 63;

    const size_t aOff0 = (size_t)(tileM + r0) * K + c0;
    const size_t aOff1 = (size_t)(tileM + r1) * K + c1;
    const size_t bOff0 = (size_t)(tileN + r0) * K + c0;
    const size_t bOff1 = (size_t)(tileN + r1) * K + c1;

    // fragment read pattern: row = lane&15 within 16-block, k = (lane>>4)*16
    const int fr = lane & 15;
    const int fk = (lane >> 4) * 16;

    v4i acc[4][4] = {};   // 4x4 grid of 16x16 accum (64 regs)

    for (int k0 = 0; k0 < K; k0 += BK) {
        async16(&lA[sIdx0], A + aOff0 + k0);
        async16(&lA[sIdx1], A + aOff1 + k0);
        async16(&lB[sIdx0], Bw + bOff0 + k0);
        async16(&lB[sIdx1], Bw + bOff1 + k0);
        __syncthreads();   // drains vmcnt (global_load_lds) + barrier

        v4i a[4], b[4];
#pragma unroll
        for (int i = 0; i < 4; ++i)
            a[i] = *(const v4i*)&lA[(wm + i * 16 + fr) * BK + fk];
#pragma unroll
        for (int j = 0; j < 4; ++j)
            b[j] = *(const v4i*)&lB[(wn + j * 16 + fr) * BK + fk];

#pragma unroll
        for (int i = 0; i < 4; ++i)
#pragma unroll
            for (int j = 0; j < 4; ++j)
                acc[i][j] = __builtin_amdgcn_mfma_i32_16x16x64_i8(
                    a[i], b[j], acc[i][j], 0, 0, 0);

        __syncthreads();   // protect LDS from next iteration's staging
    }

    const float alpha = *alpha_ptr;
    const int rr = (lane >> 4) * 4;   // C/D row group
    const int cc = lane & 15;         // C/D col
#pragma unroll
    for (int i = 0; i < 4; ++i) {
#pragma unroll
        for (int j = 0; j < 4; ++j) {
            const int row = tileM + wm + i * 16 + rr;
            const int col = tileN + wn + j * 16 + cc;
            float* p = C + (size_t)row * N + col;
#pragma unroll
            for (int r = 0; r < 4; ++r)
                p[(size_t)r * N] = (float)acc[i][j][r] * alpha;
        }
    }
}

extern "C" void kernel_launch(void* const* d_in, const int* in_sizes, int n_in,
                              void* d_out, int out_size, void* d_ws, size_t ws_size,
                              hipStream_t stream) {
    const float* x       = (const float*)d_in[0];
    const int*   w32     = (const int*)d_in[1];     // int8 ref -> int32 on device
    const float* alpha   = (const float*)d_in[2];
    const float* inscale = (const float*)d_in[3];
    float*       out     = (float*)d_out;

    const int K = 4096;
    const int N = 4096;
    const int M = in_sizes[0] / K;    // 8192

    signed char* q  = (signed char*)d_ws;                         // 32 MiB
    signed char* w8 = (signed char*)d_ws + (size_t)M * K;         // +16 MiB

    const int nw_chunks = (N * K) / 16;
    pack_w_kernel<<<(nw_chunks + 255) / 256, 256, 0, stream>>>(w32, w8, nw_chunks);

    const int nq_chunks = (M * K) / 16;
    quant_kernel<<<(nq_chunks + 255) / 256, 256, 0, stream>>>(x, q, inscale, nq_chunks);

    dim3 grid(N / BN, M / BM);   // 32 x 64 = 2048 blocks
    w8a8_gemm<<<grid, NTHREADS, 0, stream>>>(q, w8, out, alpha, M, N, K);
}

// Round 3
// 425.919 us; speedup vs baseline: 1.0196x; 1.0196x over previous
//
#include <hip/hip_runtime.h>
#include <hip/hip_bf16.h>
#include <cstdint>

// ---------------------------------------------------------------------------
// W8A8 linear: y = (int8_gemm(quant(x), W^T)) * alpha
//   x: fp32 [M=8192, K=4096]
//   W: int8 in reference -> harness materializes as int32 (const int*),
//      packed to int8 in d_ws by the prep kernel.
//   q = clip(rint(x / inscale), -128, 127) int8
// ---------------------------------------------------------------------------

typedef int v4i __attribute__((ext_vector_type(4)));

#define BM 128
#define BN 128
#define BK 64          // one MFMA K-step (16x16x64 i8)
#define NTHREADS 256

// ---- fused prologue: quant x (blocks [0,nqb)) + pack w (rest) -------------
// One element-group per thread, lane-contiguous 16B loads / 4B stores.
__global__ void prep_kernel(const float* __restrict__ x,
                            signed char* __restrict__ q,
                            const int* __restrict__ w32,
                            signed char* __restrict__ w8,
                            const float* __restrict__ inscale_ptr,
                            int nq_threads) {
    const int i = blockIdx.x * blockDim.x + threadIdx.x;
    if (i < nq_threads) {
        // quantize 4 floats -> 4 int8 (one dword)
        const float s = *inscale_ptr;
        float4 f = ((const float4*)x)[i];
        union { signed char c[4]; int v; } u;
        float vals[4] = {f.x, f.y, f.z, f.w};
#pragma unroll
        for (int e = 0; e < 4; ++e) {
            // IEEE divide + rint (round-half-even) matches np.round(xf/inscale)
            float r = rintf(vals[e] / s);
            r = fminf(fmaxf(r, -128.0f), 127.0f);
            u.c[e] = (signed char)(int)r;
        }
        ((int*)q)[i] = u.v;
    } else {
        // pack 4 int32 -> 4 int8 (one dword)
        const int j = i - nq_threads;
        int4 w = ((const int4*)w32)[j];
        union { signed char c[4]; int v; } u;
        u.c[0] = (signed char)w.x;
        u.c[1] = (signed char)w.y;
        u.c[2] = (signed char)w.z;
        u.c[3] = (signed char)w.w;
        ((int*)w8)[j] = u.v;
    }
}

// ---- async global->LDS, 16B per lane --------------------------------------
__device__ __forceinline__ void async16(void* lds, const void* g) {
    __builtin_amdgcn_global_load_lds(
        (const __attribute__((address_space(1))) void*)g,
        (__attribute__((address_space(3))) void*)lds,
        16, 0, 0);
}

// ---- int8 GEMM: C[m,n] = sum_k A[m,k]*W[n,k], epilogue *alpha -> fp32 -----
__global__ __launch_bounds__(NTHREADS)
void w8a8_gemm(const signed char* __restrict__ A,   // [M,K] quantized acts
               const signed char* __restrict__ Bw,  // [N,K] packed weights
               float* __restrict__ C,               // [M,N] fp32 out
               const float* __restrict__ alpha_ptr,
               int M, int N, int K) {
    __shared__ signed char lA[BM * BK];   // 8 KiB, contiguous (global_load_lds)
    __shared__ signed char lB[BN * BK];   // 8 KiB

    const int t    = threadIdx.x;
    const int lane = t & 63;
    const int wave = t >> 6;
    const int wm   = (wave >> 1) * 64;    // wave's row offset in tile (2x2 waves)
    const int wn   = (wave & 1) * 64;

    const int tileM = blockIdx.y * BM;
    const int tileN = blockIdx.x * BN;

    // staging: tile is 128 rows x 64 bytes = 8192 B; 256 thr x 16 B = 4096 B/step
    const int sIdx0 = t * 16;             // step-0 byte index in tile
    const int sIdx1 = sIdx0 + 4096;       // step-1
    const int r0 = sIdx0 >> 6, c0 = sIdx0 & 63;
    const int r1 = sIdx1 >> 6, c1 = sIdx1 & 63;

    const size_t aOff0 = (size_t)(tileM + r0) * K + c0;
    const size_t aOff1 = (size_t)(tileM + r1) * K + c1;
    const size_t bOff0 = (size_t)(tileN + r0) * K + c0;
    const size_t bOff1 = (size_t)(tileN + r1) * K + c1;

    // fragment read pattern: row = lane&15 within 16-block, k = (lane>>4)*16
    const int fr = lane & 15;
    const int fk = (lane >> 4) * 16;

    v4i acc[4][4] = {};   // 4x4 grid of 16x16 accum (64 regs)

    for (int k0 = 0; k0 < K; k0 += BK) {
        async16(&lA[sIdx0], A + aOff0 + k0);
        async16(&lA[sIdx1], A + aOff1 + k0);
        async16(&lB[sIdx0], Bw + bOff0 + k0);
        async16(&lB[sIdx1], Bw + bOff1 + k0);
        __syncthreads();   // drains vmcnt (global_load_lds) + barrier

        v4i a[4], b[4];
#pragma unroll
        for (int i = 0; i < 4; ++i)
            a[i] = *(const v4i*)&lA[(wm + i * 16 + fr) * BK + fk];
#pragma unroll
        for (int j = 0; j < 4; ++j)
            b[j] = *(const v4i*)&lB[(wn + j * 16 + fr) * BK + fk];

#pragma unroll
        for (int i = 0; i < 4; ++i)
#pragma unroll
            for (int j = 0; j < 4; ++j)
                acc[i][j] = __builtin_amdgcn_mfma_i32_16x16x64_i8(
                    a[i], b[j], acc[i][j], 0, 0, 0);

        __syncthreads();   // protect LDS from next iteration's staging
    }

    const float alpha = *alpha_ptr;
    const int rr = (lane >> 4) * 4;   // C/D row group
    const int cc = lane & 15;         // C/D col
#pragma unroll
    for (int i = 0; i < 4; ++i) {
#pragma unroll
        for (int j = 0; j < 4; ++j) {
            const int row = tileM + wm + i * 16 + rr;
            const int col = tileN + wn + j * 16 + cc;
            float* p = C + (size_t)row * N + col;
#pragma unroll
            for (int r = 0; r < 4; ++r)
                p[(size_t)r * N] = (float)acc[i][j][r] * alpha;
        }
    }
}

extern "C" void kernel_launch(void* const* d_in, const int* in_sizes, int n_in,
                              void* d_out, int out_size, void* d_ws, size_t ws_size,
                              hipStream_t stream) {
    const float* x       = (const float*)d_in[0];
    const int*   w32     = (const int*)d_in[1];     // int8 ref -> int32 on device
    const float* alpha   = (const float*)d_in[2];
    const float* inscale = (const float*)d_in[3];
    float*       out     = (float*)d_out;

    const int K = 4096;
    const int N = 4096;
    const int M = in_sizes[0] / K;    // 8192

    signed char* q  = (signed char*)d_ws;                         // 32 MiB
    signed char* w8 = (signed char*)d_ws + (size_t)M * K;         // +16 MiB

    const int nq_threads = (M * K) / 4;           // 8.39M (float4 each)
    const int nw_threads = (N * K) / 4;           // 4.19M (int4 each)
    const int total      = nq_threads + nw_threads;
    prep_kernel<<<(total + 255) / 256, 256, 0, stream>>>(x, q, w32, w8, inscale,
                                                         nq_threads);

    dim3 grid(N / BN, M / BM);   // 32 x 64 = 2048 blocks
    w8a8_gemm<<<grid, NTHREADS, 0, stream>>>(q, w8, out, alpha, M, N, K);
}

// Round 4
// 420.556 us; speedup vs baseline: 1.0326x; 1.0128x over previous
//
#include <hip/hip_runtime.h>
#include <hip/hip_bf16.h>
#include <cstdint>

// ---------------------------------------------------------------------------
// W8A8 linear: y = (int8_gemm(quant(x), W^T)) * alpha
//   x: fp32 [M=8192, K=4096]
//   W: int8 in reference -> harness materializes as int32 (const int*),
//      packed to int8 in d_ws by the prep kernel.
//   q = clip(rint(x / inscale), -128, 127) int8
//
// GEMM: 128x128 tile, BK=64, 4 waves (2x2), wave=64x64 as 2x2 of
// v_mfma_i32_32x32x32_i8. LDS stored as XOR-swizzled 16B chunks:
//   chunk(row r, kgroup g) -> index r*4 + (g ^ (r&3))
// so fragment ds_read_b128 spreads rows over bank-quads (kills the
// 1.7e7 SQ_LDS_BANK_CONFLICT of the natural 64B-row layout).
// ---------------------------------------------------------------------------

typedef int v4i  __attribute__((ext_vector_type(4)));
typedef int v16i __attribute__((ext_vector_type(16)));

#define BM 128
#define BN 128
#define BK 64          // K bytes per tile-step (2 k-steps of the K=32 MFMA)
#define NTHREADS 256

// ---- fused prologue: quant x (threads [0,nq)) + pack w (rest) -------------
__global__ void prep_kernel(const float* __restrict__ x,
                            signed char* __restrict__ q,
                            const int* __restrict__ w32,
                            signed char* __restrict__ w8,
                            const float* __restrict__ inscale_ptr,
                            int nq_threads) {
    const int i = blockIdx.x * blockDim.x + threadIdx.x;
    if (i < nq_threads) {
        const float s = *inscale_ptr;
        float4 f = ((const float4*)x)[i];
        union { signed char c[4]; int v; } u;
        float vals[4] = {f.x, f.y, f.z, f.w};
#pragma unroll
        for (int e = 0; e < 4; ++e) {
            // IEEE divide + rint (round-half-even) matches np.round(xf/inscale)
            float r = rintf(vals[e] / s);
            r = fminf(fmaxf(r, -128.0f), 127.0f);
            u.c[e] = (signed char)(int)r;
        }
        ((int*)q)[i] = u.v;
    } else {
        const int j = i - nq_threads;
        int4 w = ((const int4*)w32)[j];
        union { signed char c[4]; int v; } u;
        u.c[0] = (signed char)w.x;
        u.c[1] = (signed char)w.y;
        u.c[2] = (signed char)w.z;
        u.c[3] = (signed char)w.w;
        ((int*)w8)[j] = u.v;
    }
}

// ---- async global->LDS, 16B per lane --------------------------------------
__device__ __forceinline__ void async16(void* lds, const void* g) {
    __builtin_amdgcn_global_load_lds(
        (const __attribute__((address_space(1))) void*)g,
        (__attribute__((address_space(3))) void*)lds,
        16, 0, 0);
}

// ---- int8 GEMM: C[m,n] = sum_k A[m,k]*W[n,k], epilogue *alpha -> fp32 -----
__global__ __launch_bounds__(NTHREADS, 4)
void w8a8_gemm(const signed char* __restrict__ A,   // [M,K] quantized acts
               const signed char* __restrict__ Bw,  // [N,K] packed weights
               float* __restrict__ C,               // [M,N] fp32 out
               const float* __restrict__ alpha_ptr,
               int M, int N, int K) {
    __shared__ signed char lA[BM * BK];   // 8 KiB, swizzled chunk layout
    __shared__ signed char lB[BN * BK];   // 8 KiB

    const int t    = threadIdx.x;
    const int lane = t & 63;
    const int wave = t >> 6;
    const int wm   = (wave >> 1) * 64;    // wave row offset (2x2 waves)
    const int wn   = (wave & 1) * 64;

    const int tileM = blockIdx.y * BM;
    const int tileN = blockIdx.x * BN;

    // ---- staging source addresses (swizzle-aware) ----
    // chunk index i in [0,512): holds global (r = i>>2, g = (i&3)^(r&3)).
    // LDS dest is forced contiguous: chunk i at byte i*16 (global_load_lds).
    const int i0 = t;              // step 0 chunk
    const int i1 = t + NTHREADS;   // step 1 chunk
    const int r0 = i0 >> 2, g0 = (i0 & 3) ^ (r0 & 3);
    const int r1 = i1 >> 2, g1 = (i1 & 3) ^ (r1 & 3);

    const size_t aOff0 = (size_t)(tileM + r0) * K + g0 * 16;
    const size_t aOff1 = (size_t)(tileM + r1) * K + g1 * 16;
    const size_t bOff0 = (size_t)(tileN + r0) * K + g0 * 16;
    const size_t bOff1 = (size_t)(tileN + r1) * K + g1 * 16;

    // ---- fragment read pattern (32x32x32 i8): ----
    // A[m = lane&31][k = (lane>>5)*16 + j], j=0..15 -> one b128 per frag
    const int mrow  = lane & 31;
    const int khalf = lane >> 5;          // 0 or 1

    // swizzled byte address of frag chunk (row, kgroup)
    auto fragAddr = [&](int row, int fg) -> int {
        return (row * 4 + (fg ^ (row & 3))) * 16;
    };

    v16i acc[2][2] = {};   // 2x2 grid of 32x32 accum (64 AGPRs)

    for (int k0 = 0; k0 < K; k0 += BK) {
        async16(&lA[i0 * 16], A + aOff0 + k0);
        async16(&lA[i1 * 16], A + aOff1 + k0);
        async16(&lB[i0 * 16], Bw + bOff0 + k0);
        async16(&lB[i1 * 16], Bw + bOff1 + k0);
        __syncthreads();   // drains vmcnt (global_load_lds) + barrier

        v4i a[2][2], b[2][2];   // [im/jn][kstep]
#pragma unroll
        for (int s = 0; s < 2; ++s) {
            const int fg = 2 * s + khalf;
#pragma unroll
            for (int im = 0; im < 2; ++im)
                a[im][s] = *(const v4i*)&lA[fragAddr(wm + im * 32 + mrow, fg)];
#pragma unroll
            for (int jn = 0; jn < 2; ++jn)
                b[jn][s] = *(const v4i*)&lB[fragAddr(wn + jn * 32 + mrow, fg)];
        }

#pragma unroll
        for (int s = 0; s < 2; ++s)
#pragma unroll
            for (int im = 0; im < 2; ++im)
#pragma unroll
                for (int jn = 0; jn < 2; ++jn)
                    acc[im][jn] = __builtin_amdgcn_mfma_i32_32x32x32_i8(
                        a[im][s], b[jn][s], acc[im][jn], 0, 0, 0);

        __syncthreads();   // protect LDS from next iteration's staging
    }

    // ---- epilogue: C/D layout col=lane&31, row=(reg&3)+8*(reg>>2)+4*(lane>>5)
    const float alpha = *alpha_ptr;
    const int ccol  = lane & 31;
    const int rquad = (lane >> 5) * 4;
#pragma unroll
    for (int im = 0; im < 2; ++im) {
#pragma unroll
        for (int jn = 0; jn < 2; ++jn) {
            const int baseRow = tileM + wm + im * 32;
            const int col     = tileN + wn + jn * 32 + ccol;
#pragma unroll
            for (int reg = 0; reg < 16; ++reg) {
                const int row = baseRow + (reg & 3) + 8 * (reg >> 2) + rquad;
                C[(size_t)row * N + col] = (float)acc[im][jn][reg] * alpha;
            }
        }
    }
}

extern "C" void kernel_launch(void* const* d_in, const int* in_sizes, int n_in,
                              void* d_out, int out_size, void* d_ws, size_t ws_size,
                              hipStream_t stream) {
    const float* x       = (const float*)d_in[0];
    const int*   w32     = (const int*)d_in[1];     // int8 ref -> int32 on device
    const float* alpha   = (const float*)d_in[2];
    const float* inscale = (const float*)d_in[3];
    float*       out     = (float*)d_out;

    const int K = 4096;
    const int N = 4096;
    const int M = in_sizes[0] / K;    // 8192

    signed char* q  = (signed char*)d_ws;                         // 32 MiB
    signed char* w8 = (signed char*)d_ws + (size_t)M * K;         // +16 MiB

    const int nq_threads = (M * K) / 4;           // float4 each
    const int nw_threads = (N * K) / 4;           // int4 each
    const int total      = nq_threads + nw_threads;
    prep_kernel<<<(total + 255) / 256, 256, 0, stream>>>(x, q, w32, w8, inscale,
                                                         nq_threads);

    dim3 grid(N / BN, M / BM);   // 32 x 64 = 2048 blocks
    w8a8_gemm<<<grid, NTHREADS, 0, stream>>>(q, w8, out, alpha, M, N, K);
}